// Round 8
// baseline (151.732 us; speedup 1.0000x reference)
//
#include <hip/hip_runtime.h>
#include <hip/hip_bf16.h>
#include <hip/hip_fp8.h>
#include <math.h>

typedef float floatx4 __attribute__((ext_vector_type(4)));
typedef float floatx16 __attribute__((ext_vector_type(16)));
typedef int i32x4 __attribute__((ext_vector_type(4)));
typedef int i32x8 __attribute__((ext_vector_type(8)));
typedef long long i64;

#define N_ROWS 4096
#define DIM 512
#define LAM 0.5f
#define NT 64                      // 128-row block-tiles per dim (8192/128)
#define NTILES (NT * (NT + 1) / 2) // 2080 triangular tiles
#define GRID 512                   // persistent: 2 blocks/CU (64 KB LDS each)

#define GLOBAL_AS(p) ((const __attribute__((address_space(1))) void*)(p))
#define LDS_AS(p) ((__attribute__((address_space(3))) void*)(p))

__device__ __forceinline__ unsigned int pack4_fp8(float a, float b, float c, float d) {
    unsigned int u0 = __hip_cvt_float_to_fp8(a, __HIP_SATFINITE, __HIP_E4M3);
    unsigned int u1 = __hip_cvt_float_to_fp8(b, __HIP_SATFINITE, __HIP_E4M3);
    unsigned int u2 = __hip_cvt_float_to_fp8(c, __HIP_SATFINITE, __HIP_E4M3);
    unsigned int u3 = __hip_cvt_float_to_fp8(d, __HIP_SATFINITE, __HIP_E4M3);
    return u0 | (u1 << 8) | (u2 << 16) | (u3 << 24);
}

// One wave per row: L2-normalize 512 fp32 -> fp8 e4m3. NEW (MX round): Z is
// stored K-LINEAR (no q-permutation; the 32x32x64 f8f6f4 operand wants 32
// consecutive k-bytes per lane) with only the 16-B chunk XOR swizzle:
// chunk ch (k = ch*16..ch*16+15) stored at physical p = ch ^ (row & 7).
// XOR touches only the low 3 bits -> each 128-B group is closed under it,
// so the GEMM stages BK=128 panels as plain physical byte copies.
__global__ __launch_bounds__(256) void normalize_kernel(
    const float* __restrict__ ei, const float* __restrict__ ej,
    unsigned char* __restrict__ Z, float* __restrict__ out) {
    if (blockIdx.x == 0 && threadIdx.x == 0) out[0] = 0.0f;
    const int w = threadIdx.x >> 6, lane = threadIdx.x & 63;
    const int row = blockIdx.x * 4 + w;                     // [0, 8192)
    const float* __restrict__ src = (row < N_ROWS)
        ? (ei + (size_t)row * DIM)
        : (ej + (size_t)(row - N_ROWS) * DIM);
    const float4* src4 = (const float4*)src;
    float4 v0 = src4[lane];
    float4 v1 = src4[lane + 64];
    float s = v0.x*v0.x + v0.y*v0.y + v0.z*v0.z + v0.w*v0.w
            + v1.x*v1.x + v1.y*v1.y + v1.z*v1.z + v1.w*v1.w;
    #pragma unroll
    for (int off = 32; off; off >>= 1) s += __shfl_xor(s, off);
    const float r = rsqrtf(s);

    __shared__ __align__(16) unsigned char buf[4][512];     // k-linear fp8 rows
    ((unsigned int*)buf[w])[lane]      = pack4_fp8(v0.x*r, v0.y*r, v0.z*r, v0.w*r);
    ((unsigned int*)buf[w])[lane + 64] = pack4_fp8(v1.x*r, v1.y*r, v1.z*r, v1.w*r);
    __syncthreads();

    // full-wave swizzled store: lane = ch*2 + h, 8 B each (k-linear source)
    const int ch = lane >> 1, h2 = lane & 1;
    i64 val = *(const i64*)(buf[w] + ch * 16 + h2 * 8);
    const int p = ch ^ (row & 7);                           // chunk swizzle
    *(i64*)(Z + (size_t)row * DIM + p * 16 + h2 * 8) = val;
}

// Fused S = Z.Z^T + loss reduction.
// R7 post-mortem: direct-L2 gather REGRESSED (50.2 us; 16-line/instr gather
// costs more in TA/L1-miss than LDS relay saved in barriers) -> LDS-staged
// R2 schedule restored (128^2 tile, 4 waves, BK=128 dbuf, 64 KB, 2 blocks/CU,
// persistent, continuous single-barrier pipeline). Five structural attacks on
// the ~3400cyc/stage stall all failed -> shrink the PIPE term instead:
// NEW this round: MX-scaled MFMA v_mfma_scale_f32_32x32x64_f8f6f4 with fp8
// inputs + unit scales (e8m0=127 -> 2^0): 4686 TF ubench vs 2190 plain fp8,
// MFMA floor 17 -> 8.5 us. Per wave per stage: 8 MFMAs (2x2 frags x 2 K=64
// groups). Operand layout: row = lane&31, k = (lane>>5)*32 + byte (CDNA
// pattern generalized from the verified 16x16x32 fp8 map); fragment = two
// swizzled ds_read_b128 (k-ascending). C/D 32x32 map: col = lane&31,
// row = (reg&3) + 8*(reg>>2) + 4*(lane>>5)  (verified, shape-determined).
__global__ __launch_bounds__(256, 2) void simloss_kernel(
    const unsigned char* __restrict__ Z, float* __restrict__ out) {
    const int tid = threadIdx.x;
    const int w = tid >> 6, lane = tid & 63;
    const int r5 = lane & 31, h = lane >> 5;   // MFMA operand row / k-half
    const int rx = r5 & 7;                     // chunk-swizzle key
    const int wm = w & 1, wn = w >> 1;

    __shared__ __align__(16) unsigned char As[2][128 * 128];  // 16 KB per buf
    __shared__ __align__(16) unsigned char Bs[2][128 * 128];
    __shared__ float red[4];

    // staging (unchanged): wave w, instr l: rows w*8 + (lane>>3) + l*32,
    // byte (lane&7)*16; LDS slot = l*4096 + w*1024 + lane*16 (lane-linear)
    const int stRow = w * 8 + (lane >> 3);
    const int stCol = (lane & 7) * 16;
    const int ldsOff = w * 1024;

    const int bid = blockIdx.x;
    const int nMine = 4 + ((bid & 15) == 0);   // 2080 = 512*4 + 32 extras

    auto decode = [](int id, int& bm, int& bn) {
        int m = (int)((2*NT + 1 - sqrtf((float)((2*NT+1)*(2*NT+1)) - 8.0f * (float)id)) * 0.5f);
        if (m < 0) m = 0; if (m > NT-1) m = NT-1;
        while ((m + 1) * NT - ((m + 1) * m) / 2 <= id) ++m;
        while (m * NT - (m * (m - 1)) / 2 > id) --m;
        bm = m;
        bn = m + (id - (m * NT - (m * (m - 1)) / 2));
    };
    auto tileIdx = [bid](int mt) {
        return (mt < 4) ? (bid + mt * GRID) : (4 * GRID + (bid >> 4));
    };

    int bm, bn; decode(tileIdx(0), bm, bn);
    const unsigned char* stA = Z + (size_t)(bm * 128 + stRow) * DIM + stCol;
    const unsigned char* stB = Z + (size_t)(bn * 128 + stRow) * DIM + stCol;

    float negsum = 0.0f, possum = 0.0f;

    #define ISSUE(par, pA, pB, kOff)                                             \
        _Pragma("unroll")                                                        \
        for (int l = 0; l < 4; ++l) {                                            \
            __builtin_amdgcn_global_load_lds(GLOBAL_AS((pA) + (size_t)l * 32 * DIM + (kOff)), \
                                             LDS_AS(&As[par][ldsOff + l * 4096]), 16, 0, 0); \
            __builtin_amdgcn_global_load_lds(GLOBAL_AS((pB) + (size_t)l * 32 * DIM + (kOff)), \
                                             LDS_AS(&Bs[par][ldsOff + l * 4096]), 16, 0, 0); \
        }

    // prologue: tile 0, stage 0 -> buf 0
    ISSUE(0, stA, stB, 0)

    for (int mt = 0; mt < nMine; ++mt) {
        const bool hasNext = (mt + 1 < nMine);
        int nbm = 0, nbn = 0;
        const unsigned char *nA = stA, *nB = stB;
        if (hasNext) {
            decode(tileIdx(mt + 1), nbm, nbn);
            nA = Z + (size_t)(nbm * 128 + stRow) * DIM + stCol;
            nB = Z + (size_t)(nbn * 128 + stRow) * DIM + stCol;
        }

        floatx16 acc[2][2] = {};   // 2x2 of 32x32 output frags (64x64/wave)

        #pragma unroll
        for (int s = 0; s < 4; ++s) {
            const int par = (mt * 4 + s) & 1;   // continuous buffer parity
            asm volatile("s_waitcnt vmcnt(0)" ::: "memory");
            __builtin_amdgcn_sched_barrier(0);
            __builtin_amdgcn_s_barrier();       // publishes stage-s LDS
            if (s < 3)        { ISSUE(par ^ 1, stA, stB, (s + 1) * 128) }
            else if (hasNext) { ISSUE(par ^ 1, nA, nB, 0) }

            const unsigned char* fraA = &As[par][(wm * 64 + r5) * 128];
            const unsigned char* fraB = &Bs[par][(wn * 64 + r5) * 128];
            #pragma unroll
            for (int g2 = 0; g2 < 2; ++g2) {    // two K=64 groups per stage
                // lane's 32 k-bytes = chunks lc, lc+1 (lc even) at swizzled
                // positions; (lc+1)^rx = (lc^rx)^1 -> o1 = o0 ^ 16
                const int o0 = ((g2 * 4 + h * 2) ^ rx) << 4;
                const int o1 = o0 ^ 16;
                i32x4 al0 = *(const i32x4*)(fraA + o0);
                i32x4 al1 = *(const i32x4*)(fraA + o1);
                i32x4 am0 = *(const i32x4*)(fraA + 32 * 128 + o0);
                i32x4 am1 = *(const i32x4*)(fraA + 32 * 128 + o1);
                i32x4 bl0 = *(const i32x4*)(fraB + o0);
                i32x4 bl1 = *(const i32x4*)(fraB + o1);
                i32x4 bm0 = *(const i32x4*)(fraB + 32 * 128 + o0);
                i32x4 bm1 = *(const i32x4*)(fraB + 32 * 128 + o1);
                i32x8 a0 = __builtin_shufflevector(al0, al1, 0,1,2,3,4,5,6,7);
                i32x8 a1 = __builtin_shufflevector(am0, am1, 0,1,2,3,4,5,6,7);
                i32x8 b0 = __builtin_shufflevector(bl0, bl1, 0,1,2,3,4,5,6,7);
                i32x8 b1 = __builtin_shufflevector(bm0, bm1, 0,1,2,3,4,5,6,7);
                // cbsz=0 (A fp8), blgp=0 (B fp8), scales = e8m0 127 = 1.0
                acc[0][0] = __builtin_amdgcn_mfma_scale_f32_32x32x64_f8f6f4(a0, b0, acc[0][0], 0, 0, 0, 127, 0, 127);
                acc[0][1] = __builtin_amdgcn_mfma_scale_f32_32x32x64_f8f6f4(a0, b1, acc[0][1], 0, 0, 0, 127, 0, 127);
                acc[1][0] = __builtin_amdgcn_mfma_scale_f32_32x32x64_f8f6f4(a1, b0, acc[1][0], 0, 0, 0, 127, 0, 127);
                acc[1][1] = __builtin_amdgcn_mfma_scale_f32_32x32x64_f8f6f4(a1, b1, acc[1][1], 0, 0, 0, 127, 0, 127);
            }
        }

        // --- epilogue (no barriers; next tile's loads in flight) ---
        // C/D: global row = bm*128 + wm*64 + i*32 + (reg&3)+8*(reg>>2)+4*h,
        //      global col = bn*128 + wn*64 + j*32 + r5
        const int tm = bm * 2 + wm, tn = bn * 2 + wn;   // 64-unit tile ids
        const float wgt = (tn < tm) ? 0.0f : ((tn == tm) ? 1.0f : 2.0f);
        const bool hasPos = (tn == tm + 64);            // wave-uniform
        if (wgt != 0.0f) {
            float nacc = 0.0f;
            #pragma unroll
            for (int j = 0; j < 2; ++j) {
                const int cg = tn * 64 + j * 32 + r5;
                float p = 1.0f;
                #pragma unroll
                for (int i = 0; i < 2; ++i) {
                    const int rbase = tm * 64 + i * 32 + 4 * h;
                    #pragma unroll
                    for (int reg = 0; reg < 16; ++reg) {
                        const int rg = rbase + (reg & 3) + 8 * (reg >> 2);
                        const float sv = acc[i][j][reg];
                        float e = __expf(sv - LAM);
                        if (rg == cg) e = 0.0f;           // main diagonal
                        p *= (1.0f + e);
                        if (hasPos && cg == rg + N_ROWS)  // positive pair
                            possum += log1pf(expf(-sv + LAM));
                    }
                }
                nacc += __logf(p);
            }
            negsum += nacc * wgt;
        }

        bm = nbm; bn = nbn; stA = nA; stB = nB;
    }

    // --- block reduction: one atomic per block ---
    #pragma unroll
    for (int off = 32; off; off >>= 1) {
        negsum += __shfl_xor(negsum, off);
        possum += __shfl_xor(possum, off);
    }
    const float part = negsum * (1.0f / (12.0f * (float)N_ROWS))
                     + possum * (1.0f / (float)N_ROWS);
    if (lane == 0) red[w] = part;
    __syncthreads();
    if (tid == 0) atomicAdd(out, red[0] + red[1] + red[2] + red[3]);
    #undef ISSUE
}

extern "C" void kernel_launch(void* const* d_in, const int* in_sizes, int n_in,
                              void* d_out, int out_size, void* d_ws, size_t ws_size,
                              hipStream_t stream) {
    const float* ei = (const float*)d_in[0];
    const float* ej = (const float*)d_in[1];
    float* out = (float*)d_out;
    unsigned char* Z = (unsigned char*)d_ws;  // 8192*512 fp8 = 4 MB scratch

    normalize_kernel<<<2048, 256, 0, stream>>>(ei, ej, Z, out);
    simloss_kernel<<<GRID, 256, 0, stream>>>(Z, out);
}

// Round 9
// 106.383 us; speedup vs baseline: 1.4263x; 1.4263x over previous
//
#include <hip/hip_runtime.h>
#include <hip/hip_bf16.h>
#include <hip/hip_fp8.h>
#include <math.h>

typedef float floatx4 __attribute__((ext_vector_type(4)));
typedef long long i64;
typedef long long i64x2 __attribute__((ext_vector_type(2)));

#define N_ROWS 4096
#define DIM 512
#define LAM 0.5f
#define NT 64                      // 128-row block-tiles per dim (8192/128)
#define NTILES (NT * (NT + 1) / 2) // 2080 triangular tiles
#define GRID 512                   // persistent: 2 blocks/CU

#define GLOBAL_AS(p) ((const __attribute__((address_space(1))) void*)(p))
#define LDS_AS(p) ((__attribute__((address_space(3))) void*)(p))

__device__ __forceinline__ unsigned int pack4_fp8(float a, float b, float c, float d) {
    unsigned int u0 = __hip_cvt_float_to_fp8(a, __HIP_SATFINITE, __HIP_E4M3);
    unsigned int u1 = __hip_cvt_float_to_fp8(b, __HIP_SATFINITE, __HIP_E4M3);
    unsigned int u2 = __hip_cvt_float_to_fp8(c, __HIP_SATFINITE, __HIP_E4M3);
    unsigned int u3 = __hip_cvt_float_to_fp8(d, __HIP_SATFINITE, __HIP_E4M3);
    return u0 | (u1 << 8) | (u2 << 16) | (u3 << 24);
}

// One wave per row: L2-normalize 512 fp32 -> fp8 e4m3, stored K-PERMUTED and
// chunk-swizzled. 16-B chunk ch = kt*4+q (kt: 64-k group, q: MFMA quad) holds
// k = kt*64 + {q*8..q*8+7 (lo 8B), 32+q*8..+7 (hi 8B)}; chunk stored at
// physical position p = ch ^ (row & 3). NOTE: 2-bit XOR now (was &7): the
// GEMM stages BK=64 (one 64-B chunk-group per stage) and only a low-2-bit
// XOR keeps each 4-chunk-aligned 64-B group closed under the permutation,
// so staging remains a plain physical byte copy.
__global__ __launch_bounds__(256) void normalize_kernel(
    const float* __restrict__ ei, const float* __restrict__ ej,
    unsigned char* __restrict__ Z, float* __restrict__ out) {
    if (blockIdx.x == 0 && threadIdx.x == 0) out[0] = 0.0f;
    const int w = threadIdx.x >> 6, lane = threadIdx.x & 63;
    const int row = blockIdx.x * 4 + w;                     // [0, 8192)
    const float* __restrict__ src = (row < N_ROWS)
        ? (ei + (size_t)row * DIM)
        : (ej + (size_t)(row - N_ROWS) * DIM);
    const float4* src4 = (const float4*)src;
    float4 v0 = src4[lane];
    float4 v1 = src4[lane + 64];
    float s = v0.x*v0.x + v0.y*v0.y + v0.z*v0.z + v0.w*v0.w
            + v1.x*v1.x + v1.y*v1.y + v1.z*v1.z + v1.w*v1.w;
    #pragma unroll
    for (int off = 32; off; off >>= 1) s += __shfl_xor(s, off);
    const float r = rsqrtf(s);

    __shared__ __align__(16) unsigned char buf[4][512];     // k-linear fp8 rows
    ((unsigned int*)buf[w])[lane]      = pack4_fp8(v0.x*r, v0.y*r, v0.z*r, v0.w*r);
    ((unsigned int*)buf[w])[lane + 64] = pack4_fp8(v1.x*r, v1.y*r, v1.z*r, v1.w*r);
    __syncthreads();

    // full-wave permuted store: lane = kt*8 + q*2 + h, 8 B each
    const int kt = lane >> 3, q = (lane >> 1) & 3, h = lane & 1;
    i64 val = *(const i64*)(buf[w] + kt * 64 + h * 32 + q * 8);
    const int p = (kt * 4 + q) ^ (row & 3);                 // 2-bit chunk swizzle
    *(i64*)(Z + (size_t)row * DIM + p * 16 + h * 8) = val;
}

// Fused S = Z.Z^T (fp8 16x16x32 MFMA) + loss reduction.
// R8 post-mortem: MX path correct but spilled ~300 MB scratch (VGPR cap 128
// w/ 64-AGPR acc) -> closed. Base = R2 structure (best 100.8).
// NEW this round - the last untested stall theory: stage loads LAND LATE
// (global_load_lds DMA writes starve against 8 waves of ds_read on the LDS
// port), so the per-stage vmcnt(0) is the ~3-4K cyc serial phase and nothing
// inside the compute phase could show an effect (consistent w/ R3/R4/R6 all
// flat). Distinguishing experiment = TRUE T4: prefetch DEPTH 2 + counted
// vmcnt, never 0 mid-loop:
//   * BK=64, TRIPLE-buffered (3 x (8KB A + 8KB B) = 48 KB, 2 blocks/CU).
//   * Stage g issues stage g+2's 4 loads; top-of-stage wait = vmcnt(4)
//     (leaves stage g+1's 4 in flight; stage-g loads guaranteed landed);
//     vmcnt(0) only for the final stage.
//   * 8 stages/tile; per stage/wave: 8 ds_read_b128 + 32 MFMA.
//   * Z swizzle now 2-bit (see normalize) -> fragment reads are ~4-way bank
//     conflicted (1.58x on an ~35%-loaded LDS pipe - accepted cost of BK=64
//     closure).
__global__ __launch_bounds__(256, 2) void simloss_kernel(
    const unsigned char* __restrict__ Z, float* __restrict__ out) {
    const int tid = threadIdx.x;
    const int w = tid >> 6, lane = tid & 63;
    const int q = lane >> 4, m16 = lane & 15;
    const int wm = w & 1, wn = w >> 1;

    __shared__ __align__(16) unsigned char As[3][128 * 64];  // 8 KB per buf
    __shared__ __align__(16) unsigned char Bs[3][128 * 64];
    __shared__ float red[4];

    const int fragSwz = m16 & 3;
    // staging: wave w, instr l (0..1): rows w*32 + l*16 + (lane>>2),
    // 16-B chunk (lane&3); LDS dest = base + w*2048 + l*1024 + lane*16
    // (lane-monotone: (lane>>2)=row-in-16 (stride 64 B), (lane&3)=chunk)
    const int stRow = w * 32 + (lane >> 2);
    const int stCol = (lane & 3) * 16;
    const int ldsOff = w * 2048;

    const int bid = blockIdx.x;
    const int nMine = 4 + ((bid & 15) == 0);   // 2080 = 512*4 + 32 extras

    auto decode = [](int id, int& bm, int& bn) {
        int m = (int)((2*NT + 1 - sqrtf((float)((2*NT+1)*(2*NT+1)) - 8.0f * (float)id)) * 0.5f);
        if (m < 0) m = 0; if (m > NT-1) m = NT-1;
        while ((m + 1) * NT - ((m + 1) * m) / 2 <= id) ++m;
        while (m * NT - (m * (m - 1)) / 2 > id) --m;
        bm = m;
        bn = m + (id - (m * NT - (m * (m - 1)) / 2));
    };
    auto tileIdx = [bid](int mt) {
        return (mt < 4) ? (bid + mt * GRID) : (4 * GRID + (bid >> 4));
    };

    int bm, bn; decode(tileIdx(0), bm, bn);
    const unsigned char* stA = Z + (size_t)(bm * 128 + stRow) * DIM + stCol;
    const unsigned char* stB = Z + (size_t)(bn * 128 + stRow) * DIM + stCol;

    float negsum = 0.0f, possum = 0.0f;

    // one BK=64 stage: A panel 128x64B (2 instr/wave) + B panel (2 instr/wave)
    // = 4 loads/thread/stage
    #define ISSUE(b, pA, pB, kOff)                                               \
        _Pragma("unroll")                                                        \
        for (int l = 0; l < 2; ++l) {                                            \
            __builtin_amdgcn_global_load_lds(GLOBAL_AS((pA) + (size_t)l * 16 * DIM + (kOff)), \
                                             LDS_AS(&As[b][ldsOff + l * 1024]), 16, 0, 0); \
            __builtin_amdgcn_global_load_lds(GLOBAL_AS((pB) + (size_t)l * 16 * DIM + (kOff)), \
                                             LDS_AS(&Bs[b][ldsOff + l * 1024]), 16, 0, 0); \
        }

    // prologue: stages 0,1 of tile 0 -> bufs 0,1
    ISSUE(0, stA, stB, 0)
    ISSUE(1, stA, stB, 64)

    for (int mt = 0; mt < nMine; ++mt) {
        const bool hasNext = (mt + 1 < nMine);
        int nbm = 0, nbn = 0;
        const unsigned char *nA = stA, *nB = stB;
        if (hasNext) {
            decode(tileIdx(mt + 1), nbm, nbn);
            nA = Z + (size_t)(nbm * 128 + stRow) * DIM + stCol;
            nB = Z + (size_t)(nbn * 128 + stRow) * DIM + stCol;
        }

        floatx4 acc[4][4] = {};

        #pragma unroll
        for (int u = 0; u < 8; ++u) {           // 8 BK=64 stages per tile
            const int g = mt * 8 + u;           // global stage counter
            const int b = g % 3;                // buffer index
            // counted wait: outstanding = stage g (oldest 4) + stage g+1 (4);
            // vmcnt(4) -> stage-g loads landed, g+1's stay in flight.
            // Final stage overall: nothing newer -> drain.
            if (u == 7 && !hasNext) { asm volatile("s_waitcnt vmcnt(0)" ::: "memory"); }
            else                    { asm volatile("s_waitcnt vmcnt(4)" ::: "memory"); }
            __builtin_amdgcn_sched_barrier(0);
            __builtin_amdgcn_s_barrier();       // all waves' stage-g data in LDS;
                                                // all waves done reading buf[(g-1)%3]
            // issue stage g+2 into buf[(g+2)%3] = buf[(g-1)%3]
            if (u < 6)         { ISSUE((g + 2) % 3, stA, stB, (u + 2) * 64) }
            else if (hasNext)  { ISSUE((g + 2) % 3, nA, nB, (u - 6) * 64) }

            // fragments: one K=64 group; chunk q at swizzled pos q^(m16&3)
            const unsigned char* fraA = &As[b][(wm * 64 + m16) * 64];
            const unsigned char* fraB = &Bs[b][(wn * 64 + m16) * 64];
            const int cOff = (q ^ fragSwz) << 4;
            i64x2 af[4], bf[4];
            #pragma unroll
            for (int i = 0; i < 4; ++i) af[i] = *(const i64x2*)(fraA + i * 16 * 64 + cOff);
            #pragma unroll
            for (int j = 0; j < 4; ++j) bf[j] = *(const i64x2*)(fraB + j * 16 * 64 + cOff);
            __builtin_amdgcn_s_setprio(1);
            // x-pass (16 independent), then y-pass (dep distance 16)
            #pragma unroll
            for (int i = 0; i < 4; ++i)
                #pragma unroll
                for (int j = 0; j < 4; ++j)
                    acc[i][j] = __builtin_amdgcn_mfma_f32_16x16x32_fp8_fp8(af[i].x, bf[j].x, acc[i][j], 0, 0, 0);
            #pragma unroll
            for (int i = 0; i < 4; ++i)
                #pragma unroll
                for (int j = 0; j < 4; ++j)
                    acc[i][j] = __builtin_amdgcn_mfma_f32_16x16x32_fp8_fp8(af[i].y, bf[j].y, acc[i][j], 0, 0, 0);
            __builtin_amdgcn_s_setprio(0);
        }

        // --- epilogue (no barriers; next tile's loads in flight) ---
        // C/D map: row = i*16 + q*4 + r, col = j*16 + m16 (tile-local)
        const int tm = bm * 2 + wm, tn = bn * 2 + wn;   // 64-unit tile ids
        const float wgt = (tn < tm) ? 0.0f : ((tn == tm) ? 1.0f : 2.0f);
        const bool hasPos = (tn == tm + 64);            // wave-uniform
        if (wgt != 0.0f) {
            const int rowBase = tm * 64 + q * 4;
            const int colBase = tn * 64 + m16;
            float nacc = 0.0f;
            #pragma unroll
            for (int j = 0; j < 4; ++j) {
                const int cg = colBase + j * 16;
                float p = 1.0f;
                #pragma unroll
                for (int i = 0; i < 4; ++i) {
                    const int rg0 = rowBase + i * 16;
                    #pragma unroll
                    for (int r = 0; r < 4; ++r) {
                        const float sv = acc[i][j][r];
                        float e = __expf(sv - LAM);
                        if (rg0 + r == cg) e = 0.0f;          // main diagonal
                        p *= (1.0f + e);
                        if (hasPos && cg == rg0 + r + N_ROWS) // positive pair
                            possum += log1pf(expf(-sv + LAM));
                    }
                }
                nacc += __logf(p);
            }
            negsum += nacc * wgt;
        }

        bm = nbm; bn = nbn; stA = nA; stB = nB;
    }

    // --- block reduction: one atomic per block ---
    #pragma unroll
    for (int off = 32; off; off >>= 1) {
        negsum += __shfl_xor(negsum, off);
        possum += __shfl_xor(possum, off);
    }
    const float part = negsum * (1.0f / (12.0f * (float)N_ROWS))
                     + possum * (1.0f / (float)N_ROWS);
    if (lane == 0) red[w] = part;
    __syncthreads();
    if (tid == 0) atomicAdd(out, red[0] + red[1] + red[2] + red[3]);
    #undef ISSUE
}

extern "C" void kernel_launch(void* const* d_in, const int* in_sizes, int n_in,
                              void* d_out, int out_size, void* d_ws, size_t ws_size,
                              hipStream_t stream) {
    const float* ei = (const float*)d_in[0];
    const float* ej = (const float*)d_in[1];
    float* out = (float*)d_out;
    unsigned char* Z = (unsigned char*)d_ws;  // 8192*512 fp8 = 4 MB scratch

    normalize_kernel<<<2048, 256, 0, stream>>>(ei, ej, Z, out);
    simloss_kernel<<<GRID, 256, 0, stream>>>(Z, out);
}

// Round 10
// 105.897 us; speedup vs baseline: 1.4328x; 1.0046x over previous
//
#include <hip/hip_runtime.h>
#include <hip/hip_bf16.h>
#include <hip/hip_fp8.h>
#include <math.h>

typedef float floatx4 __attribute__((ext_vector_type(4)));
typedef long long i64;
typedef long long i64x2 __attribute__((ext_vector_type(2)));

#define N_ROWS 4096
#define DIM 512
#define LAM 0.5f
#define NT 64                      // 128-row block-tiles per dim (8192/128)
#define NTILES (NT * (NT + 1) / 2) // 2080 triangular tiles
#define GRID 512                   // persistent: 2 blocks/CU

#define GLOBAL_AS(p) ((const __attribute__((address_space(1))) void*)(p))
#define LDS_AS(p) ((__attribute__((address_space(3))) void*)(p))

__device__ __forceinline__ unsigned int pack4_fp8(float a, float b, float c, float d) {
    unsigned int u0 = __hip_cvt_float_to_fp8(a, __HIP_SATFINITE, __HIP_E4M3);
    unsigned int u1 = __hip_cvt_float_to_fp8(b, __HIP_SATFINITE, __HIP_E4M3);
    unsigned int u2 = __hip_cvt_float_to_fp8(c, __HIP_SATFINITE, __HIP_E4M3);
    unsigned int u3 = __hip_cvt_float_to_fp8(d, __HIP_SATFINITE, __HIP_E4M3);
    return u0 | (u1 << 8) | (u2 << 16) | (u3 << 24);
}

// One wave per row: L2-normalize 512 fp32 -> fp8 e4m3, stored K-PERMUTED and
// chunk-swizzled. 16-B chunk ch = kt*4+q (kt: 64-k group, q: MFMA quad) holds
// k = kt*64 + {q*8..q*8+7 (lo 8B), 32+q*8..+7 (hi 8B)}; chunk stored at
// physical position p = ch ^ (row & 3). 2-bit XOR: the GEMM stages BK=64
// (one 64-B chunk-group per stage) and a low-2-bit XOR keeps each 4-chunk
// 64-B group closed under the permutation -> plain physical byte copies.
__global__ __launch_bounds__(256) void normalize_kernel(
    const float* __restrict__ ei, const float* __restrict__ ej,
    unsigned char* __restrict__ Z, float* __restrict__ out) {
    if (blockIdx.x == 0 && threadIdx.x == 0) out[0] = 0.0f;
    const int w = threadIdx.x >> 6, lane = threadIdx.x & 63;
    const int row = blockIdx.x * 4 + w;                     // [0, 8192)
    const float* __restrict__ src = (row < N_ROWS)
        ? (ei + (size_t)row * DIM)
        : (ej + (size_t)(row - N_ROWS) * DIM);
    const float4* src4 = (const float4*)src;
    float4 v0 = src4[lane];
    float4 v1 = src4[lane + 64];
    float s = v0.x*v0.x + v0.y*v0.y + v0.z*v0.z + v0.w*v0.w
            + v1.x*v1.x + v1.y*v1.y + v1.z*v1.z + v1.w*v1.w;
    #pragma unroll
    for (int off = 32; off; off >>= 1) s += __shfl_xor(s, off);
    const float r = rsqrtf(s);

    __shared__ __align__(16) unsigned char buf[4][512];     // k-linear fp8 rows
    ((unsigned int*)buf[w])[lane]      = pack4_fp8(v0.x*r, v0.y*r, v0.z*r, v0.w*r);
    ((unsigned int*)buf[w])[lane + 64] = pack4_fp8(v1.x*r, v1.y*r, v1.z*r, v1.w*r);
    __syncthreads();

    // full-wave permuted store: lane = kt*8 + q*2 + h, 8 B each
    const int kt = lane >> 3, q = (lane >> 1) & 3, h = lane & 1;
    i64 val = *(const i64*)(buf[w] + kt * 64 + h * 32 + q * 8);
    const int p = (kt * 4 + q) ^ (row & 3);                 // 2-bit chunk swizzle
    *(i64*)(Z + (size_t)row * DIM + p * 16 + h * 8) = val;
}

// Fused S = Z.Z^T (fp8 16x16x32 MFMA) + loss reduction.
// R9 post-mortem: BK=64 cooperative DOUBLED the per-tile barrier joins and
// ran ~6us WORSE -> the per-stage cross-wave join is the pacer (consistent
// with R5 worse / R6 flat / R3,R4 flat). NEW this round - REMOVE THE JOINS:
//   * PRIVATE per-wave staging: each wave DMAs its OWN 64-row A panel and
//     64-row B panel (64 B k-chunk per stage) into a private LDS double
//     buffer (2 x 8 KB/wave, 64 KB/block, 2 blocks/CU). A/B duplication x2
//     -> ~532 MB DMA via L2 (~15 us aggregate at 34.5 TB/s), lane-monotone
//     1-KB-per-instruction copies (NOT R7's 16-line gather).
//   * ZERO s_barrier in the main loop. Per-wave self-paced pipeline: issue
//     next stage's 8 loads -> counted vmcnt(8) (per-wave counter, counts
//     own loads only) -> 8 ds_read_b128 -> 32 MFMA. Buffer reuse needs no
//     sync: the only reader of a wave's buffer is the wave itself (reads
//     lgkm-drained before the prior MFMA burst consumed them).
//   * 8 stages/tile (even) -> stage-0 parity always buf0: the continuous
//     cross-tile pipeline survives tile boundaries.
//   * Waves on a SIMD (2, from different blocks) drift freely -> attn-like
//     independent regime: setprio(1) around MFMA kept (helps there, m191).
__global__ __launch_bounds__(256, 2) void simloss_kernel(
    const unsigned char* __restrict__ Z, float* __restrict__ out) {
    const int tid = threadIdx.x;
    const int w = tid >> 6, lane = tid & 63;
    const int q = lane >> 4, m16 = lane & 15;
    const int wm = w & 1, wn = w >> 1;

    // private per-wave double buffers: [parity][wave][64 rows x 64 B]
    __shared__ __align__(16) unsigned char As[2][4][4096];  // 32 KB
    __shared__ __align__(16) unsigned char Bs[2][4][4096];  // 32 KB
    __shared__ float red[4];

    const int fragSwz = m16 & 3;
    // staging: instr l (0..3): panel row l*16 + (lane>>2), 16-B chunk (lane&3)
    // LDS dest = &buf[b][w][l*1024] + lane*16 (lane-monotone byte copy)
    const int stRow = lane >> 2;
    const int stCol = (lane & 3) * 16;

    const int bid = blockIdx.x;
    const int nMine = 4 + ((bid & 15) == 0);   // 2080 = 512*4 + 32 extras

    auto decode = [](int id, int& bm, int& bn) {
        int m = (int)((2*NT + 1 - sqrtf((float)((2*NT+1)*(2*NT+1)) - 8.0f * (float)id)) * 0.5f);
        if (m < 0) m = 0; if (m > NT-1) m = NT-1;
        while ((m + 1) * NT - ((m + 1) * m) / 2 <= id) ++m;
        while (m * NT - (m * (m - 1)) / 2 > id) --m;
        bm = m;
        bn = m + (id - (m * NT - (m * (m - 1)) / 2));
    };
    auto tileIdx = [bid](int mt) {
        return (mt < 4) ? (bid + mt * GRID) : (4 * GRID + (bid >> 4));
    };

    int bm, bn; decode(tileIdx(0), bm, bn);
    // per-wave panel bases (wave's own 64 rows of A and of B)
    const unsigned char* stA = Z + (size_t)(bm * 128 + wm * 64 + stRow) * DIM + stCol;
    const unsigned char* stB = Z + (size_t)(bn * 128 + wn * 64 + stRow) * DIM + stCol;

    float negsum = 0.0f, possum = 0.0f;

    // one BK=64 stage, PRIVATE: 4 A loads + 4 B loads (8 total, 1 KB each)
    #define ISSUE(b, pA, pB, kOff)                                               \
        _Pragma("unroll")                                                        \
        for (int l = 0; l < 4; ++l) {                                            \
            __builtin_amdgcn_global_load_lds(GLOBAL_AS((pA) + (size_t)l * 16 * DIM + (kOff)), \
                                             LDS_AS(&As[b][w][l * 1024]), 16, 0, 0); \
            __builtin_amdgcn_global_load_lds(GLOBAL_AS((pB) + (size_t)l * 16 * DIM + (kOff)), \
                                             LDS_AS(&Bs[b][w][l * 1024]), 16, 0, 0); \
        }

    // prologue: tile 0, stage 0 -> buf 0
    ISSUE(0, stA, stB, 0)

    for (int mt = 0; mt < nMine; ++mt) {
        const bool hasNext = (mt + 1 < nMine);
        int nbm = 0, nbn = 0;
        const unsigned char *nA = stA, *nB = stB;
        if (hasNext) {
            decode(tileIdx(mt + 1), nbm, nbn);
            nA = Z + (size_t)(nbm * 128 + wm * 64 + stRow) * DIM + stCol;
            nB = Z + (size_t)(nbn * 128 + wn * 64 + stRow) * DIM + stCol;
        }

        floatx4 acc[4][4] = {};

        #pragma unroll
        for (int u = 0; u < 8; ++u) {           // 8 BK=64 stages per tile
            const int b = u & 1;                // buffer parity (mt*8 is even)
            // issue stage u+1 into buf b^1 (its prior contents, stage u-1,
            // were fully read by THIS wave last iteration - no sync needed)
            if (u < 7)        { ISSUE(b ^ 1, stA, stB, (u + 1) * 64) }
            else if (hasNext) { ISSUE(b ^ 1, nA, nB, 0) }
            // counted wait: 8 newer (stage u+1) stay in flight; stage-u landed
            if (u == 7 && !hasNext) { asm volatile("s_waitcnt vmcnt(0)" ::: "memory"); }
            else                    { asm volatile("s_waitcnt vmcnt(8)" ::: "memory"); }
            __builtin_amdgcn_sched_barrier(0);

            // fragments from MY buffer: row m16 (+16i), chunk q^(m16&3)
            const unsigned char* fraA = &As[b][w][m16 * 64];
            const unsigned char* fraB = &Bs[b][w][m16 * 64];
            const int cOff = (q ^ fragSwz) << 4;
            i64x2 af[4], bf[4];
            #pragma unroll
            for (int i = 0; i < 4; ++i) af[i] = *(const i64x2*)(fraA + i * 1024 + cOff);
            #pragma unroll
            for (int j = 0; j < 4; ++j) bf[j] = *(const i64x2*)(fraB + j * 1024 + cOff);
            __builtin_amdgcn_s_setprio(1);
            // x-pass (16 independent), then y-pass (dep distance 16)
            #pragma unroll
            for (int i = 0; i < 4; ++i)
                #pragma unroll
                for (int j = 0; j < 4; ++j)
                    acc[i][j] = __builtin_amdgcn_mfma_f32_16x16x32_fp8_fp8(af[i].x, bf[j].x, acc[i][j], 0, 0, 0);
            #pragma unroll
            for (int i = 0; i < 4; ++i)
                #pragma unroll
                for (int j = 0; j < 4; ++j)
                    acc[i][j] = __builtin_amdgcn_mfma_f32_16x16x32_fp8_fp8(af[i].y, bf[j].y, acc[i][j], 0, 0, 0);
            __builtin_amdgcn_s_setprio(0);
        }

        // --- epilogue (no sync; next tile's stage-0 loads in flight) ---
        // C/D map: row = i*16 + q*4 + r, col = j*16 + m16 (tile-local)
        const int tm = bm * 2 + wm, tn = bn * 2 + wn;   // 64-unit tile ids
        const float wgt = (tn < tm) ? 0.0f : ((tn == tm) ? 1.0f : 2.0f);
        const bool hasPos = (tn == tm + 64);            // wave-uniform
        if (wgt != 0.0f) {
            const int rowBase = tm * 64 + q * 4;
            const int colBase = tn * 64 + m16;
            float nacc = 0.0f;
            #pragma unroll
            for (int j = 0; j < 4; ++j) {
                const int cg = colBase + j * 16;
                float p = 1.0f;
                #pragma unroll
                for (int i = 0; i < 4; ++i) {
                    const int rg0 = rowBase + i * 16;
                    #pragma unroll
                    for (int r = 0; r < 4; ++r) {
                        const float sv = acc[i][j][r];
                        float e = __expf(sv - LAM);
                        if (rg0 + r == cg) e = 0.0f;          // main diagonal
                        p *= (1.0f + e);
                        if (hasPos && cg == rg0 + r + N_ROWS) // positive pair
                            possum += log1pf(expf(-sv + LAM));
                    }
                }
                nacc += __logf(p);
            }
            negsum += nacc * wgt;
        }

        bm = nbm; bn = nbn; stA = nA; stB = nB;
    }

    // --- block reduction: one atomic per block ---
    #pragma unroll
    for (int off = 32; off; off >>= 1) {
        negsum += __shfl_xor(negsum, off);
        possum += __shfl_xor(possum, off);
    }
    const float part = negsum * (1.0f / (12.0f * (float)N_ROWS))
                     + possum * (1.0f / (float)N_ROWS);
    if (lane == 0) red[w] = part;
    __syncthreads();
    if (tid == 0) atomicAdd(out, red[0] + red[1] + red[2] + red[3]);
    #undef ISSUE
}

extern "C" void kernel_launch(void* const* d_in, const int* in_sizes, int n_in,
                              void* d_out, int out_size, void* d_ws, size_t ws_size,
                              hipStream_t stream) {
    const float* ei = (const float*)d_in[0];
    const float* ej = (const float*)d_in[1];
    float* out = (float*)d_out;
    unsigned char* Z = (unsigned char*)d_ws;  // 8192*512 fp8 = 4 MB scratch

    normalize_kernel<<<2048, 256, 0, stream>>>(ei, ej, Z, out);
    simloss_kernel<<<GRID, 256, 0, stream>>>(Z, out);
}